// Round 28
// baseline (140.224 us; speedup 1.0000x reference)
//
#include <hip/hip_runtime.h>
#include <hip/hip_bf16.h>

typedef float f4 __attribute__((ext_vector_type(4)));
typedef unsigned int uint32;
typedef _Float16 h16;
typedef _Float16 h16x2 __attribute__((ext_vector_type(2)));
typedef _Float16 f16x8 __attribute__((ext_vector_type(8)));
typedef float f32x4v __attribute__((ext_vector_type(4)));

union h2u { uint32 u; h16 h[2]; h16x2 v; };

#define BSH 8            // 256 nodes per bucket
#define CHUNK 4096       // edges per sort workgroup
#define CAP 6144         // max edges per bucket (mean 4096, +32 sigma); also the fixed bucket stride

// ---------------- pass C (fused): chunk hist + LDS sort + padded-bucket placement (+ gbound blocks) ----------------
__global__ __launch_bounds__(256) void bscat_k(const int* __restrict__ src, const int* __restrict__ dst,
                                               int* __restrict__ bcur, unsigned int* __restrict__ bedge,
                                               const int* __restrict__ batch, int* __restrict__ gstart,
                                               int E, int B, int N, int G, int nchunk) {
    int tid = threadIdx.x;
    if (blockIdx.x >= nchunk) {   // gbound part
        int i = (blockIdx.x - nchunk) * 256 + tid;
        if (i >= N) return;
        int b = batch[i];
        int prev = (i == 0) ? -1 : batch[i - 1];
        for (int g = prev + 1; g <= b; ++g) gstart[g] = i;
        if (i == N - 1) {
            for (int g = b + 1; g <= G; ++g) gstart[g] = N;
        }
        return;
    }
    __shared__ int hist[512], lbase[512], cur2[512], gb[512];
    __shared__ int sa[512], sb[512];
    __shared__ unsigned int sedge[CHUNK];
    __shared__ unsigned short posb[CHUNK];
    int base = blockIdx.x * CHUNK;
    int n = min(CHUNK, E - base);
    for (int i = tid; i < 512; i += 256) hist[i] = 0;
    __syncthreads();
    for (int i = tid; i < n; i += 256) atomicAdd(&hist[dst[base + i] >> BSH], 1);
    __syncthreads();
    #pragma unroll
    for (int k = 0; k < 2; ++k) { int i = tid + k * 256; sa[i] = hist[i]; }
    __syncthreads();
    int* c = sa; int* nx = sb;
    for (int off = 1; off < 512; off <<= 1) {
        #pragma unroll
        for (int k = 0; k < 2; ++k) { int i = tid + k * 256; nx[i] = c[i] + (i >= off ? c[i - off] : 0); }
        __syncthreads();
        int* t = c; c = nx; nx = t;
    }
    #pragma unroll
    for (int k = 0; k < 2; ++k) {
        int i = tid + k * 256;
        int ex = c[i] - hist[i];
        lbase[i] = ex; cur2[i] = ex;
        if (i < B) gb[i] = hist[i] ? (i * CAP + atomicAdd(&bcur[i], hist[i])) : 0;
    }
    for (int t = tid; t < B; t += 256) {
        int e0 = lbase[t], e1 = e0 + hist[t];
        for (int j = e0; j < e1; ++j) posb[j] = (unsigned short)t;
    }
    __syncthreads();
    for (int i = tid; i < n; i += 256) {
        int d = dst[base + i];
        int s = src[base + i];
        int b = d >> BSH;
        int p = atomicAdd(&cur2[b], 1);
        sedge[p] = ((unsigned int)s << BSH) | (unsigned int)(d & ((1 << BSH) - 1));
    }
    __syncthreads();
    for (int i = tid; i < n; i += 256) {
        int b = posb[i];
        bedge[gb[b] + (i - lbase[b])] = sedge[i];
    }
}

// ---------------- pass D (fused): per-bucket CSR + degrees + dinv + MFMA gemm1 for the same 256 rows ----------------
union SharedU {
    struct { int hist[256], cur2[256], sa[256], sb[256]; int cols[CAP]; } p1;
    struct { h16 xS[64][136]; h16 wS[8192]; } p2;   // +8 pad kills x-read bank conflicts; wS in B-frag order
};

__global__ __launch_bounds__(256) void bcsrgemm_k(const unsigned int* __restrict__ bedge,
                                                  const int* __restrict__ bcur,
                                                  const float* __restrict__ x, const float* __restrict__ W1,
                                                  int* __restrict__ row_ptr, int* __restrict__ cnt,
                                                  float* __restrict__ dinv, int* __restrict__ col,
                                                  h16* __restrict__ hsh, int N, int B) {
    __shared__ SharedU su;
    __shared__ float sdinv[256];
    int b = blockIdx.x, tid = threadIdx.x;
    int node0 = b << BSH;
    int g0 = b * CAP;
    int n = min(bcur[b], CAP);

    // ---- phase 1: CSR ----
    su.p1.hist[tid] = 0;
    __syncthreads();
    for (int i = tid; i < n; i += 256) atomicAdd(&su.p1.hist[bedge[g0 + i] & 255], 1);
    __syncthreads();
    su.p1.sa[tid] = su.p1.hist[tid];
    __syncthreads();
    int* c = su.p1.sa; int* nx = su.p1.sb;
    for (int off = 1; off < 256; off <<= 1) {
        nx[tid] = c[tid] + (tid >= off ? c[tid - off] : 0);
        __syncthreads();
        int* t = c; c = nx; nx = t;
    }
    int ex = c[tid] - su.p1.hist[tid];
    su.p1.cur2[tid] = ex;
    int node = node0 + tid;
    {
        int deg = su.p1.hist[tid];
        float di = rsqrtf((float)(deg + 1));
        sdinv[tid] = di;
        if (node < N) {
            cnt[node] = deg;
            row_ptr[node] = g0 + ex;
            dinv[node] = di;
        }
    }
    __syncthreads();
    for (int i = tid; i < n; i += 256) {
        unsigned int e = bedge[g0 + i];
        int p = atomicAdd(&su.p1.cur2[e & 255], 1);
        if (p < CAP) su.p1.cols[p] = (int)(e >> BSH);
    }
    __syncthreads();
    for (int i = tid; i < n; i += 256) col[g0 + i] = (i < CAP) ? su.p1.cols[i] : 0;
    __syncthreads();   // p1 scratch dead beyond here

    // ---- phase 2: gemm1 (MFMA fp16) for rows node0..node0+255, 4 tiles of 64 ----
    #pragma unroll
    for (int i = 0; i < 32; ++i) {       // W1: 8192 f32, coalesced read, swizzled fp16 store
        int idx = tid + i * 256;
        int k = idx >> 6, cc = idx & 63;
        su.p2.wS[(((k >> 3) * 64) + cc) * 8 + (k & 7)] = (h16)W1[idx];
    }
    const int wv = tid >> 6;     // wave = row-tile 0..3 within the 64-row tile
    const int lane = tid & 63;
    const int q = lane >> 4;     // k-quarter / C row-group
    const int cc16 = lane & 15;  // A row / B,C col
    for (int t = 0; t < 4; ++t) {
        int trow0 = node0 + t * 64;
        #pragma unroll
        for (int it = 0; it < 8; ++it) {     // x tile: 64 rows x 32 f4
            int i = tid + it * 256;
            int r = i >> 5;
            int k4 = (i & 31) * 4;
            int row = trow0 + r;
            f4 v = (f4)(0.0f);
            if (row < N) v = *(const f4*)(x + (size_t)row * 128 + k4);
            su.p2.xS[r][k4 + 0] = (h16)v.x; su.p2.xS[r][k4 + 1] = (h16)v.y;
            su.p2.xS[r][k4 + 2] = (h16)v.z; su.p2.xS[r][k4 + 3] = (h16)v.w;
        }
        __syncthreads();
        f32x4v acc0 = {0.f, 0.f, 0.f, 0.f}, acc1 = acc0, acc2 = acc0, acc3 = acc0;
        #pragma unroll
        for (int kb = 0; kb < 4; ++kb) {
            f16x8 a = *(const f16x8*)&su.p2.xS[wv * 16 + cc16][kb * 32 + q * 8];
            const h16* wb = &su.p2.wS[(size_t)((kb * 4 + q) * 64) * 8];
            f16x8 b0 = *(const f16x8*)&wb[(0 * 16 + cc16) * 8];
            f16x8 b1 = *(const f16x8*)&wb[(1 * 16 + cc16) * 8];
            f16x8 b2 = *(const f16x8*)&wb[(2 * 16 + cc16) * 8];
            f16x8 b3 = *(const f16x8*)&wb[(3 * 16 + cc16) * 8];
            acc0 = __builtin_amdgcn_mfma_f32_16x16x32_f16(a, b0, acc0, 0, 0, 0);
            acc1 = __builtin_amdgcn_mfma_f32_16x16x32_f16(a, b1, acc1, 0, 0, 0);
            acc2 = __builtin_amdgcn_mfma_f32_16x16x32_f16(a, b2, acc2, 0, 0, 0);
            acc3 = __builtin_amdgcn_mfma_f32_16x16x32_f16(a, b3, acc3, 0, 0, 0);
        }
        #pragma unroll
        for (int j = 0; j < 4; ++j) {
            int lrow = t * 64 + wv * 16 + q * 4 + j;   // 0..255 within bucket
            int row = node0 + lrow;
            if (row < N) {
                float di = sdinv[lrow];
                size_t bo = (size_t)row * 64;
                hsh[bo +  0 + cc16] = (h16)(acc0[j] * di);
                hsh[bo + 16 + cc16] = (h16)(acc1[j] * di);
                hsh[bo + 32 + cc16] = (h16)(acc2[j] * di);
                hsh[bo + 48 + cc16] = (h16)(acc3[j] * di);
            }
        }
        __syncthreads();   // before next tile overwrites xS
    }
}

// ---------------- AGG1+GEMM2 fused: wave per node, dword (2 fp16 ch) per lane ----------------
// 16-edge unroll, packed-fp16 tree accumulate per block.
__global__ __launch_bounds__(256) void agg1_k(const h16* __restrict__ hsh, const int* __restrict__ row_ptr,
                                              const int* __restrict__ cnt, const int* __restrict__ col,
                                              const float* __restrict__ dinv, const float* __restrict__ b1,
                                              const float* __restrict__ W2, h16* __restrict__ h2sh, int N) {
    int wid = blockIdx.x * 4 + (threadIdx.x >> 6);
    int lane = threadIdx.x & 63;
    if (wid >= N) return;
    const int c16 = lane & 15;      // output channel (for the fused dot)
    const int hh  = lane >> 4;      // k-quarter 0..3
    float wreg[16];
    #pragma unroll
    for (int k = 0; k < 16; ++k) wreg[k] = W2[(hh * 16 + k) * 16 + c16];
    float bias = b1[lane];

    const int c2 = lane & 31;       // channel pair index
    const int h  = lane >> 5;       // edge subgroup 0/1
    const uint32* rowbase = (const uint32*)hsh + c2;   // + s*32 dwords = row s, channels 2c2,2c2+1

    int beg = row_ptr[wid];
    int num = cnt[wid];
    float accx = 0.0f, accy = 0.0f;
    for (int e0 = 0; e0 < num; e0 += 64) {
        int rem = num - e0;
        int el = 0;
        if (lane < rem) el = col[beg + e0 + lane];
        int m = rem < 64 ? rem : 64;
        int e = 0;
        for (; e + 16 <= m; e += 16) {     // subgroup h: 8 edges; fp16 tree then one cvt pair
            int s0 = __shfl(el, e + h);
            int s1 = __shfl(el, e + 2 + h);
            int s2 = __shfl(el, e + 4 + h);
            int s3 = __shfl(el, e + 6 + h);
            int s4 = __shfl(el, e + 8 + h);
            int s5 = __shfl(el, e + 10 + h);
            int s6 = __shfl(el, e + 12 + h);
            int s7 = __shfl(el, e + 14 + h);
            h2u u0, u1, u2, u3, u4, u5, u6, u7;
            u0.u = rowbase[(size_t)s0 * 32];
            u1.u = rowbase[(size_t)s1 * 32];
            u2.u = rowbase[(size_t)s2 * 32];
            u3.u = rowbase[(size_t)s3 * 32];
            u4.u = rowbase[(size_t)s4 * 32];
            u5.u = rowbase[(size_t)s5 * 32];
            u6.u = rowbase[(size_t)s6 * 32];
            u7.u = rowbase[(size_t)s7 * 32];
            h16x2 t01 = u0.v + u1.v;
            h16x2 t23 = u2.v + u3.v;
            h16x2 t45 = u4.v + u5.v;
            h16x2 t67 = u6.v + u7.v;
            h16x2 t03 = t01 + t23;
            h16x2 t47 = t45 + t67;
            h16x2 tt  = t03 + t47;
            accx += (float)tt[0];
            accy += (float)tt[1];
        }
        for (; e + 8 <= m; e += 8) {       // subgroup h: 4 edges
            int s0 = __shfl(el, e + h);
            int s1 = __shfl(el, e + 2 + h);
            int s2 = __shfl(el, e + 4 + h);
            int s3 = __shfl(el, e + 6 + h);
            h2u u0, u1, u2, u3;
            u0.u = rowbase[(size_t)s0 * 32];
            u1.u = rowbase[(size_t)s1 * 32];
            u2.u = rowbase[(size_t)s2 * 32];
            u3.u = rowbase[(size_t)s3 * 32];
            accx += ((float)u0.h[0] + (float)u1.h[0]) + ((float)u2.h[0] + (float)u3.h[0]);
            accy += ((float)u0.h[1] + (float)u1.h[1]) + ((float)u2.h[1] + (float)u3.h[1]);
        }
        for (; e + 4 <= m; e += 4) {       // subgroup h: edges e+h, e+2+h
            int s0 = __shfl(el, e + h);
            int s1 = __shfl(el, e + 2 + h);
            h2u u0, u1;
            u0.u = rowbase[(size_t)s0 * 32];
            u1.u = rowbase[(size_t)s1 * 32];
            accx += (float)u0.h[0] + (float)u1.h[0];
            accy += (float)u0.h[1] + (float)u1.h[1];
        }
        for (; e + 2 <= m; e += 2) {       // subgroup h: edge e+h
            int s = __shfl(el, e + h);
            h2u u; u.u = rowbase[(size_t)s * 32];
            accx += (float)u.h[0];
            accy += (float)u.h[1];
        }
        if (e < m) {                       // single leftover edge: h==0 half covers all channels
            int s = __shfl(el, e);
            if (h == 0) {
                h2u u; u.u = rowbase[(size_t)s * 32];
                accx += (float)u.h[0];
                accy += (float)u.h[1];
            }
        }
    }
    // merge the two edge subgroups
    accx += __shfl_xor(accx, 32);
    accy += __shfl_xor(accy, 32);
    // redistribute channel pairs -> lane = channel
    float ra = __shfl(accx, lane >> 1);
    float rb = __shfl(accy, lane >> 1);
    float acc = (lane & 1) ? rb : ra;

    float di = dinv[wid];
    float self = (float)hsh[(size_t)wid * 64 + lane];
    float h1v = tanhf(di * (acc + self) + bias);

    // fused h1_row @ W2: lane (hh,c16) does k = hh*16..hh*16+15, then butterfly-add quarters
    float p = 0.0f;
    #pragma unroll
    for (int k = 0; k < 16; ++k) {
        float hv = __shfl(h1v, hh * 16 + k);
        p += hv * wreg[k];
    }
    p += __shfl_xor(p, 16);
    p += __shfl_xor(p, 32);
    if (lane < 16) h2sh[(size_t)wid * 16 + lane] = (h16)(di * p);
}

// ---------------- AGG2: 16 channels, quarter-wave per node, fp16 tables both sides ----------------
__global__ __launch_bounds__(256) void agg2_k(const h16* __restrict__ h2sh, const int* __restrict__ row_ptr,
                                              const int* __restrict__ cnt, const int* __restrict__ col,
                                              const float* __restrict__ dinv, const float* __restrict__ b2,
                                              h16* __restrict__ h2h, int N) {
    int t = blockIdx.x * 256 + threadIdx.x;
    int node = t >> 4;
    int c = t & 15;
    int sub = (threadIdx.x >> 4) & 3;   // quarter within wave
    if (node >= N) return;
    int beg = row_ptr[node];
    int num = cnt[node];
    float acc = 0.0f;
    for (int e0 = 0; e0 < num; e0 += 16) {
        int rem = num - e0;
        int el = 0;
        if (c < rem) el = col[beg + e0 + c];
        int m = rem < 16 ? rem : 16;
        int e = 0;
        for (; e + 4 <= m; e += 4) {       // 4 independent loads in flight
            int s0 = __shfl(el, (sub << 4) + e + 0);
            int s1 = __shfl(el, (sub << 4) + e + 1);
            int s2 = __shfl(el, (sub << 4) + e + 2);
            int s3 = __shfl(el, (sub << 4) + e + 3);
            float v0 = (float)h2sh[(size_t)s0 * 16 + c];
            float v1 = (float)h2sh[(size_t)s1 * 16 + c];
            float v2 = (float)h2sh[(size_t)s2 * 16 + c];
            float v3 = (float)h2sh[(size_t)s3 * 16 + c];
            acc += (v0 + v1) + (v2 + v3);
        }
        for (; e < m; ++e) {
            int s = __shfl(el, (sub << 4) + e);
            acc += (float)h2sh[(size_t)s * 16 + c];
        }
    }
    float di = dinv[node];
    float self = (float)h2sh[(size_t)node * 16 + c];
    h2h[(size_t)node * 16 + c] = (h16)tanhf(di * (acc + self) + b2[c]);
}

// ---------------- segmented pool + sigmoid: one block per graph ----------------
__global__ __launch_bounds__(256) void pool_seg_k(const h16* __restrict__ h2h, const int* __restrict__ gstart,
                                                  float* __restrict__ out) {
    __shared__ float sd[16][16];   // [node-lane][channel]
    int g = blockIdx.x;
    int beg = gstart[g], end = gstart[g + 1];
    int tid = threadIdx.x;
    int c = tid & 15, r = tid >> 4;
    float acc = 0.0f;
    for (int i = beg + r; i < end; i += 16)
        acc += (float)h2h[(size_t)i * 16 + c];
    sd[r][c] = acc;
    __syncthreads();
    if (r < 8) sd[r][c] += sd[r + 8][c];
    __syncthreads();
    if (r < 4) sd[r][c] += sd[r + 4][c];
    __syncthreads();
    if (r < 2) sd[r][c] += sd[r + 2][c];
    __syncthreads();
    if (r == 0) {
        float m = (sd[0][c] + sd[1][c]) / fmaxf((float)(end - beg), 1.0f);
        out[g * 16 + c] = 1.0f / (1.0f + expf(-m));
    }
}

extern "C" void kernel_launch(void* const* d_in, const int* in_sizes, int n_in,
                              void* d_out, int out_size, void* d_ws, size_t ws_size,
                              hipStream_t stream) {
    const float* x     = (const float*)d_in[0];
    const int*   ei    = (const int*)d_in[1];
    const int*   batch = (const int*)d_in[2];
    const float* W1    = (const float*)d_in[3];
    const float* b1    = (const float*)d_in[4];
    const float* W2    = (const float*)d_in[5];
    const float* b2    = (const float*)d_in[6];
    float* out = (float*)d_out;

    const int N = in_sizes[2];
    const int E = in_sizes[1] / 2;
    const int G = out_size / 16;
    const int* src = ei;
    const int* dst = ei + E;

    const int B = (N + 255) >> 8;              // 391 buckets (must be <= 512)
    const int nchunk = (E + CHUNK - 1) / CHUNK;
    const int nbound = (N + 255) / 256;

    char* w = (char*)d_ws;
    int*   bcur     = (int*)w;    w += 512 * 4;
    int*   row_ptr  = (int*)w;    w += (size_t)N * 4;
    int*   cnt      = (int*)w;    w += (size_t)N * 4;
    float* dinv     = (float*)w;  w += (size_t)N * 4;
    int*   gstart   = (int*)w;    w += 528 * 4;          // padded so hsh stays 8B-aligned
    int*   col      = (int*)w;    w += (size_t)B * CAP * 4;
    h16*   hsh      = (h16*)w;    w += (size_t)N * 64 * 2;
    h16*   h2sh     = (h16*)w;    w += (size_t)N * 16 * 2;
    h16*   h2h      = (h16*)w;    w += (size_t)N * 16 * 2;
    unsigned int* bedge = (unsigned int*)w;  w += (size_t)B * CAP * 4;

    hipMemsetAsync(bcur, 0, 512 * 4, stream);

    bscat_k   <<<nchunk + nbound, 256, 0, stream>>>(src, dst, bcur, bedge, batch, gstart, E, B, N, G, nchunk);
    bcsrgemm_k<<<B, 256, 0, stream>>>(bedge, bcur, x, W1, row_ptr, cnt, dinv, col, hsh, N, B);

    agg1_k  <<<(N + 3) / 4, 256, 0, stream>>>(hsh, row_ptr, cnt, col, dinv, b1, W2, h2sh, N);
    agg2_k  <<<((size_t)N * 16 + 255) / 256, 256, 0, stream>>>(h2sh, row_ptr, cnt, col, dinv, b2, h2h, N);
    pool_seg_k<<<G, 256, 0, stream>>>(h2h, gstart, out);
}